// Round 9
// baseline (229.490 us; speedup 1.0000x reference)
//
#include <hip/hip_runtime.h>

// B=2, T=2048, C=1024, H=16, D=64; M1=B*T=4096; N1=3C=3072; K=C=1024
#define TT 2048
#define CC_DIM 1024
#define NH 16
#define HD 64
#define M1 4096

typedef __attribute__((ext_vector_type(8))) short short8;
typedef __attribute__((ext_vector_type(4))) short short4_t;
typedef __attribute__((ext_vector_type(4))) float f32x4;

static __device__ __forceinline__ unsigned short f2bf(float f) {
  union { float f; unsigned u; } v; v.f = f;
  unsigned r = v.u + 0x7fff + ((v.u >> 16) & 1);
  return (unsigned short)(r >> 16);
}

static __device__ __forceinline__ float fast_exp2(float x) {
#if __has_builtin(__builtin_amdgcn_exp2f)
  return __builtin_amdgcn_exp2f(x);
#else
  return exp2f(x);
#endif
}

// async 16B global -> LDS (dest = wave-uniform base + lane*16)
#define GLOAD_LDS16(g, l)                                                  \
  __builtin_amdgcn_global_load_lds(                                        \
      (const __attribute__((address_space(1))) unsigned int*)(g),          \
      (__attribute__((address_space(3))) unsigned int*)(l), 16, 0, 0)

// ---------- prep: x->bf16 conv + both weight transpose+convs, one launch ----
static __device__ __forceinline__ void transpose_body(
    const float* __restrict__ W, unsigned short* __restrict__ Wt,
    int K, int N, int bx, int by, float (*tile)[33]) {
  int tx = threadIdx.x & 31, ty = threadIdx.x >> 5;  // ty 0..7
#pragma unroll
  for (int r = 0; r < 4; ++r) {
    int k = by * 32 + ty + r * 8;
    int n = bx * 32 + tx;
    tile[ty + r * 8][tx] = W[(size_t)k * N + n];
  }
  __syncthreads();
#pragma unroll
  for (int r = 0; r < 4; ++r) {
    int n = bx * 32 + ty + r * 8;
    int k = by * 32 + tx;
    Wt[(size_t)n * K + k] = f2bf(tile[tx][ty + r * 8]);
  }
}

__global__ __launch_bounds__(256) void prep_kernel(
    const float* __restrict__ x, unsigned short* __restrict__ xb,
    const float* __restrict__ Wa, unsigned short* __restrict__ Wta,
    const float* __restrict__ Wp, unsigned short* __restrict__ Wtp) {
  __shared__ float tile[32][33];
  int blk = blockIdx.x;
  if (blk < 4096) {
    int i = (blk * 256 + threadIdx.x) * 4;
    f32x4 v = *(const f32x4*)&x[i];
    short4_t o;
    o[0] = (short)f2bf(v[0]); o[1] = (short)f2bf(v[1]);
    o[2] = (short)f2bf(v[2]); o[3] = (short)f2bf(v[3]);
    *(short4_t*)&xb[i] = o;
  } else if (blk < 4096 + 3072) {
    int t = blk - 4096;
    transpose_body(Wa, Wta, 1024, 3072, t % 96, t / 96, tile);
  } else {
    int t = blk - 7168;
    transpose_body(Wp, Wtp, 1024, 1024, t % 32, t / 32, tile);
  }
}

// ---------------- GEMMs: BK=64, XOR-swizzled LDS (conflict-free b128) -------
// Staging chunk L (16B): row r=L>>3, slot s=L&7 holds source col-chunk
// s^(r&7). Frag read for (row, col-chunk cc): slot cc^(row&7).
#define BM 128
#define BN 128
#define BK 64

__global__ __launch_bounds__(256) void gemm_qkv_kernel(
    const unsigned short* __restrict__ Ab,  // [4096][1024] bf16
    const unsigned short* __restrict__ Bt,  // [3072][1024] bf16 (n-major)
    const float* __restrict__ bias,         // [3072]
    unsigned short* __restrict__ qk,        // q at 0, k at +32*2048*64
    unsigned short* __restrict__ vt) {      // [32][64][2048]
  const int K = 1024;
  __shared__ __align__(16) unsigned short SM[BM * BK + BN * BK];  // 32 KB
  unsigned short* As = SM;
  unsigned short* Bs = SM + BM * BK;
  int tid = threadIdx.x;
  int lane = tid & 63, w = tid >> 6;
  int wm = (w >> 1) * 64, wn = (w & 1) * 64;
  int quad = lane >> 4, l16 = lane & 15;
  int mt0 = blockIdx.x * BM, nt0 = blockIdx.y * BN;

  f32x4 acc[4][4] = {};

  for (int k0 = 0; k0 < K; k0 += BK) {
#pragma unroll
    for (int t = 0; t < 4; ++t) {
      int c = tid + t * 256;                 // 0..1023 16B chunks
      int row = c >> 3, src = ((c & 7) ^ (row & 7)) * 8;
      GLOAD_LDS16(&Ab[(size_t)(mt0 + row) * K + k0 + src], &As[(t * 256 + w * 64) * 8]);
      GLOAD_LDS16(&Bt[(size_t)(nt0 + row) * K + k0 + src], &Bs[(t * 256 + w * 64) * 8]);
    }
    __syncthreads();
#pragma unroll
    for (int kk = 0; kk < 2; ++kk) {
      short8 af[4], bf[4];
#pragma unroll
      for (int i = 0; i < 4; ++i) {
        int row = wm + i * 16 + l16;
        af[i] = *(const short8*)&As[row * BK + (((kk * 4 + quad) ^ (row & 7)) * 8)];
      }
#pragma unroll
      for (int j = 0; j < 4; ++j) {
        int row = wn + j * 16 + l16;
        bf[j] = *(const short8*)&Bs[row * BK + (((kk * 4 + quad) ^ (row & 7)) * 8)];
      }
#pragma unroll
      for (int i = 0; i < 4; ++i)
#pragma unroll
        for (int j = 0; j < 4; ++j)
          acc[i][j] = __builtin_amdgcn_mfma_f32_16x16x32_bf16(af[i], bf[j], acc[i][j], 0, 0, 0);
    }
    __syncthreads();
  }

  // ---- epilogue via LDS staging: 8 coalesced 16B stores per thread ----
  unsigned short* Cs = SM;  // 128x128 bf16, chunk-XOR swizzled
  int which = nt0 >> 10;    // block is pure q, k, or v (BN=128 | 1024)
  if (which < 2) {
    // row-major staging; idx(row,col) = row*128 + ((col>>3)^(row&7))*8 + (col&7)
#pragma unroll
    for (int j = 0; j < 4; ++j) {
      int col = wn + j * 16 + l16;
      float bv = bias[nt0 + col];
#pragma unroll
      for (int i = 0; i < 4; ++i)
#pragma unroll
        for (int r = 0; r < 4; ++r) {
          int row = wm + i * 16 + quad * 4 + r;
          Cs[row * 128 + (((col >> 3) ^ (row & 7)) * 8) + (col & 7)] =
              f2bf(acc[i][j][r] + bv);
        }
    }
    __syncthreads();
    int row = tid >> 1, half = tid & 1;
    int grow = mt0 + row;
    int b = grow >> 11, t = grow & 2047;
    unsigned short* base = qk + (size_t)which * (32 * TT * HD);
#pragma unroll
    for (int k2 = 0; k2 < 8; ++k2) {
      int chunk = half * 8 + k2;
      short8 v8 = *(const short8*)&Cs[row * 128 + ((chunk ^ (row & 7)) * 8)];
      int cc = (nt0 + chunk * 8) & 1023;
      int h = cc >> 6, d0 = cc & 63;
      *(short8*)&base[((size_t)(b * NH + h) * TT + t) * HD + d0] = v8;
    }
  } else {
    // transposed staging for vt[d][t]; idx(col,row) = col*128 + ((row>>3)^(col&7))*8 + (row&7)
#pragma unroll
    for (int j = 0; j < 4; ++j) {
      int col = wn + j * 16 + l16;
      float bv = bias[nt0 + col];
#pragma unroll
      for (int i = 0; i < 4; ++i)
#pragma unroll
        for (int r = 0; r < 4; ++r) {
          int row = wm + i * 16 + quad * 4 + r;
          Cs[col * 128 + (((row >> 3) ^ (col & 7)) * 8) + (row & 7)] =
              f2bf(acc[i][j][r] + bv);
        }
    }
    __syncthreads();
    int vrow = tid >> 1, half = tid & 1;     // vrow = tile col = d index
    int cc = (nt0 + vrow) & 1023;
    int h = cc >> 6, d = cc & 63;
#pragma unroll
    for (int k2 = 0; k2 < 8; ++k2) {
      int tc = half * 8 + k2;
      short8 v8 = *(const short8*)&Cs[vrow * 128 + ((tc ^ (vrow & 7)) * 8)];
      int t0g = mt0 + tc * 8;
      int b = t0g >> 11;
      int t0 = t0g & 2047;                   // R8 bug: was t0g (missing mod T)
      *(short8*)&vt[((size_t)(b * NH + h) * HD + d) * TT + t0] = v8;
    }
  }
}

// ---------------- Flash attention (R5-best): 2 waves/block, 32 rows/wave ----
// 64-row chunks, mirrored pair (31-bx, bx) per block -> uniform 34 iters.
#define SC_LOG2E 0.1803368801111204f   // 0.125 * log2(e)
#define LOG2E 1.4426950408889634f
#define PST 72                         // P-tile LDS row stride (shorts), 144B rows

__global__ __launch_bounds__(128) void attn_kernel(
    const unsigned short* __restrict__ q,   // [32][2048][64]
    const unsigned short* __restrict__ k,   // [32][2048][64]
    const unsigned short* __restrict__ vt,  // [32][64][2048]
    const float* __restrict__ amask,        // [2][2048]
    unsigned short* __restrict__ y) {       // [4096][1024] bf16
  __shared__ __align__(16) unsigned short Ks[2][64 * HD];
  __shared__ __align__(16) unsigned short Vs[2][64 * HD];
  __shared__ __align__(16) unsigned short Ps[2][32 * PST];
  int tid = threadIdx.x, lane = tid & 63, w = tid >> 6;   // w 0..1
  int quad = lane >> 4, l16 = lane & 15;
  int bh = blockIdx.y, b = bh >> 4, h = bh & 15;
  const unsigned short* qb = q + (size_t)bh * TT * HD;
  const unsigned short* kb = k + (size_t)bh * TT * HD;
  const unsigned short* vb = vt + (size_t)bh * HD * TT;
  const float* amb = amask + b * TT;
  unsigned short* pw = &Ps[w][0];

  int rr = tid >> 3;                    // 0..15
  int csw = (tid & 7) ^ (rr & 7);       // same for all i (i*16 ≡ 0 mod 8)
  int bx = blockIdx.x;
  int chunks[2] = {31 - bx, bx};

#pragma unroll
  for (int ph = 0; ph < 2; ++ph) {
    int qc0 = chunks[ph] * 64;
    int qr0 = qc0 + w * 32;
    short8 aq[2][2];
#pragma unroll
    for (int rt = 0; rt < 2; ++rt) {
      aq[rt][0] = *(const short8*)&qb[(size_t)(qr0 + rt * 16 + l16) * HD + quad * 8];
      aq[rt][1] = *(const short8*)&qb[(size_t)(qr0 + rt * 16 + l16) * HD + 32 + quad * 8];
    }
    f32x4 o[2][4] = {};
    float lp[2][4] = {};
    int nit = (qc0 >> 6) + 1;

    const unsigned short* kp = kb + (size_t)rr * HD + csw * 8;  // += 64*HD/stage
    const unsigned short* vp = vb + (size_t)rr * TT + csw * 8;  // += 64/stage

    auto stage = [&](int buf) {
#pragma unroll
      for (int i = 0; i < 4; ++i) {
        GLOAD_LDS16(kp + (size_t)i * 16 * HD, &Ks[buf][(w * 64 + i * 128) * 8]);
        GLOAD_LDS16(vp + (size_t)i * 16 * TT, &Vs[buf][(w * 64 + i * 128) * 8]);
      }
      kp += 64 * HD;
      vp += 64;
    };

    stage(0);
    __syncthreads();
    int buf = 0;
    for (int it = 0; it < nit; ++it) {
      if (it + 1 < nit) stage(buf ^ 1);
      bool diag = (it == nit - 1);
      int kt0 = it * 64;
      // hoist V fragments (in flight during QK/softmax)
      short8 vf[4][2];
#pragma unroll
      for (int j = 0; j < 4; ++j) {
        int d = j * 16 + l16;
        int ch0 = quad ^ (d & 7), ch1 = (4 + quad) ^ (d & 7);
        vf[j][0] = *(const short8*)&Vs[buf][(d * 8 + ch0) * 8];
        vf[j][1] = *(const short8*)&Vs[buf][(d * 8 + ch1) * 8];
      }
      float am[4];
#pragma unroll
      for (int f = 0; f < 4; ++f) am[f] = amb[kt0 + f * 16 + l16] * LOG2E;
      // ---- QK^T ----
      f32x4 s[2][4];
#pragma unroll
      for (int f = 0; f < 4; ++f) {
        int row = f * 16 + l16;
        int ch0 = quad ^ (row & 7), ch1 = (4 + quad) ^ (row & 7);
        short8 bk0 = *(const short8*)&Ks[buf][(row * 8 + ch0) * 8];
        short8 bk1 = *(const short8*)&Ks[buf][(row * 8 + ch1) * 8];
#pragma unroll
        for (int rt = 0; rt < 2; ++rt) {
          f32x4 z = {};
          z = __builtin_amdgcn_mfma_f32_16x16x32_bf16(aq[rt][0], bk0, z, 0, 0, 0);
          z = __builtin_amdgcn_mfma_f32_16x16x32_bf16(aq[rt][1], bk1, z, 0, 0, 0);
          s[rt][f] = z;
        }
      }
      // ---- no-max softmax + truncating pack ----
#pragma unroll
      for (int rt = 0; rt < 2; ++rt)
#pragma unroll
        for (int r = 0; r < 4; ++r) {
          int rowq = qr0 + rt * 16 + quad * 4 + r;
#pragma unroll
          for (int f = 0; f < 4; ++f) {
            float p = fast_exp2(s[rt][f][r] * SC_LOG2E + am[f]);
            if (diag && (kt0 + f * 16 + l16 > rowq)) p = 0.f;
            union { float pf; unsigned u; } cv; cv.pf = p;
            cv.u &= 0xffff0000u;
            lp[rt][r] += cv.pf;
            pw[(rt * 16 + quad * 4 + r) * PST + f * 16 + l16] =
                (unsigned short)(cv.u >> 16);
          }
        }
      // ---- P round-trip (per-wave LDS region) ----
      short8 ap[2][2];
#pragma unroll
      for (int rt = 0; rt < 2; ++rt) {
        ap[rt][0] = *(const short8*)&pw[(rt * 16 + l16) * PST + quad * 8];
        ap[rt][1] = *(const short8*)&pw[(rt * 16 + l16) * PST + 32 + quad * 8];
      }
      // ---- PV ----
#pragma unroll
      for (int j = 0; j < 4; ++j)
#pragma unroll
        for (int rt = 0; rt < 2; ++rt) {
          o[rt][j] = __builtin_amdgcn_mfma_f32_16x16x32_bf16(ap[rt][0], vf[j][0], o[rt][j], 0, 0, 0);
          o[rt][j] = __builtin_amdgcn_mfma_f32_16x16x32_bf16(ap[rt][1], vf[j][1], o[rt][j], 0, 0, 0);
        }
      __syncthreads();
      buf ^= 1;
    }

    // ---- epilogue: reduce l over the 16 key-lanes, write y ----
#pragma unroll
    for (int rt = 0; rt < 2; ++rt) {
#pragma unroll
      for (int off = 1; off < 16; off <<= 1)
#pragma unroll
        for (int r = 0; r < 4; ++r) lp[rt][r] += __shfl_xor(lp[rt][r], off);
#pragma unroll
      for (int r = 0; r < 4; ++r) lp[rt][r] = __builtin_amdgcn_rcpf(lp[rt][r]);
#pragma unroll
      for (int j = 0; j < 4; ++j)
#pragma unroll
        for (int r = 0; r < 4; ++r) {
          int t = qr0 + rt * 16 + quad * 4 + r;
          y[((size_t)b * TT + t) * CC_DIM + h * HD + j * 16 + l16] =
              f2bf(o[rt][j][r] * lp[rt][r]);
        }
    }
  }
}

// ---------------- GEMM2: Y2b[4096][1024] @ Wt2[1024][1024]^T + b_proj ------
__global__ __launch_bounds__(256) void gemm_proj_kernel(
    const unsigned short* __restrict__ Ab,  // [4096][1024] bf16
    const unsigned short* __restrict__ Bt,  // [1024][1024] bf16 (n-major)
    const float* __restrict__ bias,         // [1024]
    float* __restrict__ out) {              // [4096][1024] fp32
  const int K = 1024;
  __shared__ __align__(16) unsigned short SM[BM * BK + BN * BK];  // 32 KB
  unsigned short* As = SM;
  unsigned short* Bs = SM + BM * BK;
  int tid = threadIdx.x;
  int lane = tid & 63, w = tid >> 6;
  int wm = (w >> 1) * 64, wn = (w & 1) * 64;
  int quad = lane >> 4, l16 = lane & 15;
  int mt0 = blockIdx.x * BM, nt0 = blockIdx.y * BN;

  f32x4 acc[4][4] = {};

  for (int k0 = 0; k0 < K; k0 += BK) {
#pragma unroll
    for (int t = 0; t < 4; ++t) {
      int c = tid + t * 256;
      int row = c >> 3, src = ((c & 7) ^ (row & 7)) * 8;
      GLOAD_LDS16(&Ab[(size_t)(mt0 + row) * K + k0 + src], &As[(t * 256 + w * 64) * 8]);
      GLOAD_LDS16(&Bt[(size_t)(nt0 + row) * K + k0 + src], &Bs[(t * 256 + w * 64) * 8]);
    }
    __syncthreads();
#pragma unroll
    for (int kk = 0; kk < 2; ++kk) {
      short8 af[4], bf[4];
#pragma unroll
      for (int i = 0; i < 4; ++i) {
        int row = wm + i * 16 + l16;
        af[i] = *(const short8*)&As[row * BK + (((kk * 4 + quad) ^ (row & 7)) * 8)];
      }
#pragma unroll
      for (int j = 0; j < 4; ++j) {
        int row = wn + j * 16 + l16;
        bf[j] = *(const short8*)&Bs[row * BK + (((kk * 4 + quad) ^ (row & 7)) * 8)];
      }
#pragma unroll
      for (int i = 0; i < 4; ++i)
#pragma unroll
        for (int j = 0; j < 4; ++j)
          acc[i][j] = __builtin_amdgcn_mfma_f32_16x16x32_bf16(af[i], bf[j], acc[i][j], 0, 0, 0);
    }
    __syncthreads();
  }

  // ---- epilogue via LDS (fp32, 2 passes of 64 rows), f32x4 stores ----
  float* Cf = (float*)SM;   // 64x128 fp32; idx = row2*128 + ((col>>2)^(row2&7))*4 + (col&3)
#pragma unroll
  for (int p = 0; p < 2; ++p) {
    if ((w >> 1) == p) {
#pragma unroll
      for (int j = 0; j < 4; ++j) {
        int col = wn + j * 16 + l16;
        float bv = bias[nt0 + col];
#pragma unroll
        for (int i = 0; i < 4; ++i)
#pragma unroll
          for (int r = 0; r < 4; ++r) {
            int row2 = i * 16 + quad * 4 + r;     // 0..63 (wm == p*64)
            Cf[row2 * 128 + (((col >> 2) ^ (row2 & 7)) * 4) + (col & 3)] =
                acc[i][j][r] + bv;
          }
      }
    }
    __syncthreads();
    int row2 = tid >> 2, q4 = tid & 3;
#pragma unroll
    for (int k2 = 0; k2 < 8; ++k2) {
      int col0 = q4 * 32 + k2 * 4;
      f32x4 v4 = *(const f32x4*)&Cf[row2 * 128 + (((col0 >> 2) ^ (row2 & 7)) * 4)];
      *(f32x4*)&out[(size_t)(mt0 + p * 64 + row2) * 1024 + nt0 + col0] = v4;
    }
    __syncthreads();
  }
}

extern "C" void kernel_launch(void* const* d_in, const int* in_sizes, int n_in,
                              void* d_out, int out_size, void* d_ws, size_t ws_size,
                              hipStream_t stream) {
  const float* x      = (const float*)d_in[0];
  const float* amask  = (const float*)d_in[1];
  // d_in[2] = attention_bias (tril causal) -> implemented analytically
  const float* W_attn = (const float*)d_in[3];
  const float* b_attn = (const float*)d_in[4];
  const float* W_proj = (const float*)d_in[5];
  const float* b_proj = (const float*)d_in[6];
  float* out = (float*)d_out;

  char* ws = (char*)d_ws;
  unsigned short* Xb  = (unsigned short*)ws;                               // 8 MB (reused as Y2b)
  unsigned short* Wt1 = (unsigned short*)(ws + (size_t)8  * 1024 * 1024);  // 6 MB
  unsigned short* Wt2 = (unsigned short*)(ws + (size_t)14 * 1024 * 1024);  // 2 MB
  unsigned short* qk  = (unsigned short*)(ws + (size_t)16 * 1024 * 1024);  // 16 MB (q then k)
  unsigned short* vt  = (unsigned short*)(ws + (size_t)32 * 1024 * 1024);  // 8 MB

  hipLaunchKernelGGL(prep_kernel, dim3(8192), dim3(256), 0, stream,
                     x, Xb, W_attn, Wt1, W_proj, Wt2);
  hipLaunchKernelGGL(gemm_qkv_kernel, dim3(32, 24), dim3(256), 0, stream, Xb, Wt1, b_attn, qk, vt);
  hipLaunchKernelGGL(attn_kernel, dim3(16, 32), dim3(128), 0, stream,
                     qk, qk + (size_t)32 * TT * HD, vt, amask, Xb);
  hipLaunchKernelGGL(gemm_proj_kernel, dim3(32, 8), dim3(256), 0, stream, Xb, Wt2, b_proj, out);
}

// Round 10
// 216.665 us; speedup vs baseline: 1.0592x; 1.0592x over previous
//
#include <hip/hip_runtime.h>

// B=2, T=2048, C=1024, H=16, D=64; M1=B*T=4096; N1=3C=3072; K=C=1024
#define TT 2048
#define CC_DIM 1024
#define NH 16
#define HD 64
#define M1 4096

typedef __attribute__((ext_vector_type(8))) short short8;
typedef __attribute__((ext_vector_type(4))) short short4_t;
typedef __attribute__((ext_vector_type(4))) float f32x4;

static __device__ __forceinline__ unsigned short f2bf(float f) {
  union { float f; unsigned u; } v; v.f = f;
  unsigned r = v.u + 0x7fff + ((v.u >> 16) & 1);
  return (unsigned short)(r >> 16);
}

static __device__ __forceinline__ float fast_exp2(float x) {
#if __has_builtin(__builtin_amdgcn_exp2f)
  return __builtin_amdgcn_exp2f(x);
#else
  return exp2f(x);
#endif
}

// async 16B global -> LDS (dest = wave-uniform base + lane*16)
#define GLOAD_LDS16(g, l)                                                  \
  __builtin_amdgcn_global_load_lds(                                        \
      (const __attribute__((address_space(1))) unsigned int*)(g),          \
      (__attribute__((address_space(3))) unsigned int*)(l), 16, 0, 0)

// ---------- prep: x->bf16 conv + both weight transpose+convs, one launch ----
static __device__ __forceinline__ void transpose_body(
    const float* __restrict__ W, unsigned short* __restrict__ Wt,
    int K, int N, int bx, int by, float (*tile)[33]) {
  int tx = threadIdx.x & 31, ty = threadIdx.x >> 5;  // ty 0..7
#pragma unroll
  for (int r = 0; r < 4; ++r) {
    int k = by * 32 + ty + r * 8;
    int n = bx * 32 + tx;
    tile[ty + r * 8][tx] = W[(size_t)k * N + n];
  }
  __syncthreads();
#pragma unroll
  for (int r = 0; r < 4; ++r) {
    int n = bx * 32 + ty + r * 8;
    int k = by * 32 + tx;
    Wt[(size_t)n * K + k] = f2bf(tile[tx][ty + r * 8]);
  }
}

__global__ __launch_bounds__(256) void prep_kernel(
    const float* __restrict__ x, unsigned short* __restrict__ xb,
    const float* __restrict__ Wa, unsigned short* __restrict__ Wta,
    const float* __restrict__ Wp, unsigned short* __restrict__ Wtp) {
  __shared__ float tile[32][33];
  int blk = blockIdx.x;
  if (blk < 4096) {
    int i = (blk * 256 + threadIdx.x) * 4;
    f32x4 v = *(const f32x4*)&x[i];
    short4_t o;
    o[0] = (short)f2bf(v[0]); o[1] = (short)f2bf(v[1]);
    o[2] = (short)f2bf(v[2]); o[3] = (short)f2bf(v[3]);
    *(short4_t*)&xb[i] = o;
  } else if (blk < 4096 + 3072) {
    int t = blk - 4096;
    transpose_body(Wa, Wta, 1024, 3072, t % 96, t / 96, tile);
  } else {
    int t = blk - 7168;
    transpose_body(Wp, Wtp, 1024, 1024, t % 32, t / 32, tile);
  }
}

// ---------------- GEMM1: BK=64, XOR-swizzled LDS, scalar epilogue (R7) ------
#define BM 128
#define BN 128
#define BK 64

__global__ __launch_bounds__(256) void gemm_qkv_kernel(
    const unsigned short* __restrict__ Ab,  // [4096][1024] bf16
    const unsigned short* __restrict__ Bt,  // [3072][1024] bf16 (n-major)
    const float* __restrict__ bias,         // [3072]
    unsigned short* __restrict__ qk,        // q at 0, k at +32*2048*64
    unsigned short* __restrict__ vt) {      // [32][64][2048]
  const int K = 1024;
  __shared__ __align__(16) unsigned short As[BM * BK];
  __shared__ __align__(16) unsigned short Bs[BN * BK];
  int tid = threadIdx.x;
  int lane = tid & 63, w = tid >> 6;
  int wm = (w >> 1) * 64, wn = (w & 1) * 64;
  int quad = lane >> 4, l16 = lane & 15;
  int mt0 = blockIdx.x * BM, nt0 = blockIdx.y * BN;

  f32x4 acc[4][4] = {};

  for (int k0 = 0; k0 < K; k0 += BK) {
#pragma unroll
    for (int t = 0; t < 4; ++t) {
      int c = tid + t * 256;                 // 0..1023 16B chunks
      int row = c >> 3, src = ((c & 7) ^ (row & 7)) * 8;
      GLOAD_LDS16(&Ab[(size_t)(mt0 + row) * K + k0 + src], &As[(t * 256 + w * 64) * 8]);
      GLOAD_LDS16(&Bt[(size_t)(nt0 + row) * K + k0 + src], &Bs[(t * 256 + w * 64) * 8]);
    }
    __syncthreads();
#pragma unroll
    for (int kk = 0; kk < 2; ++kk) {
      short8 af[4], bf[4];
#pragma unroll
      for (int i = 0; i < 4; ++i) {
        int row = wm + i * 16 + l16;
        af[i] = *(const short8*)&As[row * BK + (((kk * 4 + quad) ^ (row & 7)) * 8)];
      }
#pragma unroll
      for (int j = 0; j < 4; ++j) {
        int row = wn + j * 16 + l16;
        bf[j] = *(const short8*)&Bs[row * BK + (((kk * 4 + quad) ^ (row & 7)) * 8)];
      }
#pragma unroll
      for (int i = 0; i < 4; ++i)
#pragma unroll
        for (int j = 0; j < 4; ++j)
          acc[i][j] = __builtin_amdgcn_mfma_f32_16x16x32_bf16(af[i], bf[j], acc[i][j], 0, 0, 0);
    }
    __syncthreads();
  }

#pragma unroll
  for (int j = 0; j < 4; ++j) {
    int gcol = nt0 + wn + j * 16 + l16;  // 0..3071
    float bv = bias[gcol];
    int which = gcol >> 10;
    int cc = gcol & 1023;
    int h = cc >> 6, d = cc & 63;
#pragma unroll
    for (int i = 0; i < 4; ++i) {
      int growb = mt0 + wm + i * 16 + quad * 4;  // + r
      if (which < 2) {
#pragma unroll
        for (int r = 0; r < 4; ++r) {
          int grow = growb + r;
          int b = grow >> 11, t = grow & 2047;
          float val = acc[i][j][r] + bv;
          qk[(size_t)which * (32 * TT * HD) + ((size_t)(b * NH + h) * TT + t) * HD + d] = f2bf(val);
        }
      } else {
        int b = growb >> 11, t = growb & 2047;  // r=0..3 stays in same b (4-aligned)
        short4_t pk;
#pragma unroll
        for (int r = 0; r < 4; ++r) pk[r] = (short)f2bf(acc[i][j][r] + bv);
        *(short4_t*)&vt[((size_t)(b * NH + h) * HD + d) * TT + t] = pk;
      }
    }
  }
}

// ---------------- Flash attention v6: software-pipelined K-loop -------------
// 2 waves/block, 32 rows/wave, mirrored chunk pair (31-bx, bx), 34 iters.
// Per iter: issue bk-reads+QK(it), then softmax+PV(it-1) from registers ->
// MFMA/LDS pipes overlap the VALU exp chain. Diagonal masking only post-loop.
#define SC_LOG2E 0.1803368801111204f   // 0.125 * log2(e)
#define LOG2E 1.4426950408889634f
#define PST 72                         // P-tile LDS row stride (shorts)

__global__ __launch_bounds__(128) void attn_kernel(
    const unsigned short* __restrict__ q,   // [32][2048][64]
    const unsigned short* __restrict__ k,   // [32][2048][64]
    const unsigned short* __restrict__ vt,  // [32][64][2048]
    const float* __restrict__ amask,        // [2][2048]
    unsigned short* __restrict__ y) {       // [4096][1024] bf16
  __shared__ __align__(16) unsigned short Ks[2][64 * HD];
  __shared__ __align__(16) unsigned short Vs[2][64 * HD];
  __shared__ __align__(16) unsigned short Ps[2][32 * PST];
  int tid = threadIdx.x, lane = tid & 63, w = tid >> 6;   // w 0..1
  int quad = lane >> 4, l16 = lane & 15;
  int bh = blockIdx.y, b = bh >> 4, h = bh & 15;
  const unsigned short* qb = q + (size_t)bh * TT * HD;
  const unsigned short* kb = k + (size_t)bh * TT * HD;
  const unsigned short* vb = vt + (size_t)bh * HD * TT;
  const float* amb = amask + b * TT;
  unsigned short* pw = &Ps[w][0];

  int rr = tid >> 3;                    // 0..15
  int csw = (tid & 7) ^ (rr & 7);       // source col-chunk swizzle
  int bx = blockIdx.x;
  int chunks[2] = {31 - bx, bx};

#pragma unroll
  for (int ph = 0; ph < 2; ++ph) {
    int qc0 = chunks[ph] * 64;
    int qr0 = qc0 + w * 32;
    short8 aq[2][2];
#pragma unroll
    for (int rt = 0; rt < 2; ++rt) {
      aq[rt][0] = *(const short8*)&qb[(size_t)(qr0 + rt * 16 + l16) * HD + quad * 8];
      aq[rt][1] = *(const short8*)&qb[(size_t)(qr0 + rt * 16 + l16) * HD + 32 + quad * 8];
    }
    f32x4 o[2][4] = {};
    float lp[2][4] = {};
    int nit = (qc0 >> 6) + 1;

    const unsigned short* kp = kb + (size_t)rr * HD + csw * 8;  // += 64*HD/stage
    const unsigned short* vp = vb + (size_t)rr * TT + csw * 8;  // += 64/stage

    auto stage = [&](int buf) {
#pragma unroll
      for (int i = 0; i < 4; ++i) {
        GLOAD_LDS16(kp + (size_t)i * 16 * HD, &Ks[buf][(w * 64 + i * 128) * 8]);
        GLOAD_LDS16(vp + (size_t)i * 16 * TT, &Vs[buf][(w * 64 + i * 128) * 8]);
      }
      kp += 64 * HD;
      vp += 64;
    };

    // softmax + PV for a saved iteration (registers + private P region only)
    f32x4 s_prev[2][4];
    short8 vf_prev[4][2];
    float am_prev[4];
    auto softmax_pv = [&](bool diag, int kt0p) {
#pragma unroll
      for (int rt = 0; rt < 2; ++rt)
#pragma unroll
        for (int r = 0; r < 4; ++r) {
          int rowq = qr0 + rt * 16 + quad * 4 + r;
#pragma unroll
          for (int f = 0; f < 4; ++f) {
            float p = fast_exp2(s_prev[rt][f][r] * SC_LOG2E + am_prev[f]);
            if (diag && (kt0p + f * 16 + l16 > rowq)) p = 0.f;
            union { float pf; unsigned u; } cv; cv.pf = p;
            cv.u &= 0xffff0000u;
            lp[rt][r] += cv.pf;
            pw[(rt * 16 + quad * 4 + r) * PST + f * 16 + l16] =
                (unsigned short)(cv.u >> 16);
          }
        }
      short8 ap[2][2];
#pragma unroll
      for (int rt = 0; rt < 2; ++rt) {
        ap[rt][0] = *(const short8*)&pw[(rt * 16 + l16) * PST + quad * 8];
        ap[rt][1] = *(const short8*)&pw[(rt * 16 + l16) * PST + 32 + quad * 8];
      }
#pragma unroll
      for (int j = 0; j < 4; ++j)
#pragma unroll
        for (int rt = 0; rt < 2; ++rt) {
          o[rt][j] = __builtin_amdgcn_mfma_f32_16x16x32_bf16(ap[rt][0], vf_prev[j][0], o[rt][j], 0, 0, 0);
          o[rt][j] = __builtin_amdgcn_mfma_f32_16x16x32_bf16(ap[rt][1], vf_prev[j][1], o[rt][j], 0, 0, 0);
        }
    };

    __syncthreads();   // protect buffers from previous phase's readers
    stage(0);
    for (int it = 0; it < nit; ++it) {
      __syncthreads();                      // tile `it` staged; buffers safe
      if (it + 1 < nit) stage((it + 1) & 1);
      int bufc = it & 1;
      int kt0 = it * 64;
      // ---- QK(it): bk reads + MFMA (fills MFMA/LDS pipes) ----
      f32x4 s_cur[2][4];
#pragma unroll
      for (int f = 0; f < 4; ++f) {
        int row = f * 16 + l16;
        int ch0 = quad ^ (row & 7), ch1 = (4 + quad) ^ (row & 7);
        short8 bk0 = *(const short8*)&Ks[bufc][(row * 8 + ch0) * 8];
        short8 bk1 = *(const short8*)&Ks[bufc][(row * 8 + ch1) * 8];
#pragma unroll
        for (int rt = 0; rt < 2; ++rt) {
          f32x4 z = {};
          z = __builtin_amdgcn_mfma_f32_16x16x32_bf16(aq[rt][0], bk0, z, 0, 0, 0);
          z = __builtin_amdgcn_mfma_f32_16x16x32_bf16(aq[rt][1], bk1, z, 0, 0, 0);
          s_cur[rt][f] = z;
        }
      }
      float am_cur[4];
#pragma unroll
      for (int f = 0; f < 4; ++f) am_cur[f] = amb[kt0 + f * 16 + l16] * LOG2E;
      // ---- softmax + PV for iter it-1 (overlaps QK(it) execution) ----
      if (it > 0) softmax_pv(false, 0);
      // ---- V fragments for iter it (vf_prev now free) ----
#pragma unroll
      for (int j = 0; j < 4; ++j) {
        int d = j * 16 + l16;
        int ch0 = quad ^ (d & 7), ch1 = (4 + quad) ^ (d & 7);
        vf_prev[j][0] = *(const short8*)&Vs[bufc][(d * 8 + ch0) * 8];
        vf_prev[j][1] = *(const short8*)&Vs[bufc][(d * 8 + ch1) * 8];
      }
      // carry
#pragma unroll
      for (int rt = 0; rt < 2; ++rt)
#pragma unroll
        for (int f = 0; f < 4; ++f) s_prev[rt][f] = s_cur[rt][f];
#pragma unroll
      for (int f = 0; f < 4; ++f) am_prev[f] = am_cur[f];
    }
    // ---- drain pipeline: last iter is the diagonal ----
    softmax_pv(true, (nit - 1) * 64);

    // ---- epilogue: reduce l over the 16 key-lanes, write y ----
#pragma unroll
    for (int rt = 0; rt < 2; ++rt) {
#pragma unroll
      for (int off = 1; off < 16; off <<= 1)
#pragma unroll
        for (int r = 0; r < 4; ++r) lp[rt][r] += __shfl_xor(lp[rt][r], off);
#pragma unroll
      for (int r = 0; r < 4; ++r) lp[rt][r] = __builtin_amdgcn_rcpf(lp[rt][r]);
#pragma unroll
      for (int j = 0; j < 4; ++j)
#pragma unroll
        for (int r = 0; r < 4; ++r) {
          int t = qr0 + rt * 16 + quad * 4 + r;
          y[((size_t)b * TT + t) * CC_DIM + h * HD + j * 16 + l16] =
              f2bf(o[rt][j][r] * lp[rt][r]);
        }
    }
  }
}

// ---------------- GEMM2: BM=64 (512 blocks, 2/CU), BK=64 swizzled -----------
#define BM2 64
#define BN2 128

__global__ __launch_bounds__(256) void gemm_proj_kernel(
    const unsigned short* __restrict__ Ab,  // [4096][1024] bf16
    const unsigned short* __restrict__ Bt,  // [1024][1024] bf16 (n-major)
    const float* __restrict__ bias,         // [1024]
    float* __restrict__ out) {              // [4096][1024] fp32
  const int K = 1024;
  __shared__ __align__(16) unsigned short As[BM2 * BK];   // 8 KB
  __shared__ __align__(16) unsigned short Bs[BN2 * BK];   // 16 KB
  int tid = threadIdx.x;
  int lane = tid & 63, w = tid >> 6;
  int wm = (w >> 1) * 32, wn = (w & 1) * 64;
  int quad = lane >> 4, l16 = lane & 15;
  int mt0 = blockIdx.x * BM2, nt0 = blockIdx.y * BN2;

  f32x4 acc[2][4] = {};

  for (int k0 = 0; k0 < K; k0 += BK) {
#pragma unroll
    for (int t = 0; t < 2; ++t) {           // A: 512 chunks
      int c = tid + t * 256;
      int row = c >> 3, src = ((c & 7) ^ (row & 7)) * 8;
      GLOAD_LDS16(&Ab[(size_t)(mt0 + row) * K + k0 + src], &As[(t * 256 + w * 64) * 8]);
    }
#pragma unroll
    for (int t = 0; t < 4; ++t) {           // B: 1024 chunks
      int c = tid + t * 256;
      int row = c >> 3, src = ((c & 7) ^ (row & 7)) * 8;
      GLOAD_LDS16(&Bt[(size_t)(nt0 + row) * K + k0 + src], &Bs[(t * 256 + w * 64) * 8]);
    }
    __syncthreads();
#pragma unroll
    for (int kk = 0; kk < 2; ++kk) {
      short8 af[2], bf[4];
#pragma unroll
      for (int i = 0; i < 2; ++i) {
        int row = wm + i * 16 + l16;
        af[i] = *(const short8*)&As[row * BK + (((kk * 4 + quad) ^ (row & 7)) * 8)];
      }
#pragma unroll
      for (int j = 0; j < 4; ++j) {
        int row = wn + j * 16 + l16;
        bf[j] = *(const short8*)&Bs[row * BK + (((kk * 4 + quad) ^ (row & 7)) * 8)];
      }
#pragma unroll
      for (int i = 0; i < 2; ++i)
#pragma unroll
        for (int j = 0; j < 4; ++j)
          acc[i][j] = __builtin_amdgcn_mfma_f32_16x16x32_bf16(af[i], bf[j], acc[i][j], 0, 0, 0);
    }
    __syncthreads();
  }

#pragma unroll
  for (int j = 0; j < 4; ++j) {
    int gcol = nt0 + wn + j * 16 + l16;
    float bv = bias[gcol];
#pragma unroll
    for (int i = 0; i < 2; ++i)
#pragma unroll
      for (int r = 0; r < 4; ++r) {
        int grow = mt0 + wm + i * 16 + quad * 4 + r;
        out[(size_t)grow * 1024 + gcol] = acc[i][j][r] + bv;
      }
  }
}

extern "C" void kernel_launch(void* const* d_in, const int* in_sizes, int n_in,
                              void* d_out, int out_size, void* d_ws, size_t ws_size,
                              hipStream_t stream) {
  const float* x      = (const float*)d_in[0];
  const float* amask  = (const float*)d_in[1];
  // d_in[2] = attention_bias (tril causal) -> implemented analytically
  const float* W_attn = (const float*)d_in[3];
  const float* b_attn = (const float*)d_in[4];
  const float* W_proj = (const float*)d_in[5];
  const float* b_proj = (const float*)d_in[6];
  float* out = (float*)d_out;

  char* ws = (char*)d_ws;
  unsigned short* Xb  = (unsigned short*)ws;                               // 8 MB (reused as Y2b)
  unsigned short* Wt1 = (unsigned short*)(ws + (size_t)8  * 1024 * 1024);  // 6 MB
  unsigned short* Wt2 = (unsigned short*)(ws + (size_t)14 * 1024 * 1024);  // 2 MB
  unsigned short* qk  = (unsigned short*)(ws + (size_t)16 * 1024 * 1024);  // 16 MB (q then k)
  unsigned short* vt  = (unsigned short*)(ws + (size_t)32 * 1024 * 1024);  // 8 MB

  hipLaunchKernelGGL(prep_kernel, dim3(8192), dim3(256), 0, stream,
                     x, Xb, W_attn, Wt1, W_proj, Wt2);
  hipLaunchKernelGGL(gemm_qkv_kernel, dim3(32, 24), dim3(256), 0, stream, Xb, Wt1, b_attn, qk, vt);
  hipLaunchKernelGGL(attn_kernel, dim3(16, 32), dim3(128), 0, stream,
                     qk, qk + (size_t)32 * TT * HD, vt, amask, Xb);
  hipLaunchKernelGGL(gemm_proj_kernel, dim3(64, 8), dim3(256), 0, stream, Xb, Wt2, b_proj, out);
}